// Round 3
// baseline (770.802 us; speedup 1.0000x reference)
//
#include <hip/hip_runtime.h>
#include <hip/hip_bf16.h>

#define B_TOT 1024
#define L_T   128
#define DIN   5
#define HD    64
#define RESN  256
#define BDN   8
#define NMAT  9
#define NROWS (NMAT * RESN)                 // 2304
#define PLANE ((size_t)NROWS * RESN)        // 589824 elems per weight plane
#define NGRP  16
#define BG    64                            // batch per group
#define FPB   16                            // features per block
#define NTHR  256                           // 4 waves = 4 independent mt-planes
#define RB_GRP_BYTES (2 * 16 * 2 * BG * FPB * 2)  // 131072 B: 2 bufs x 16 fb x 2 planes x 64 b x 16 f x 2B
#define GRP_SHORTS (RB_GRP_BYTES / 2)       // 65536 shorts per group
#define BUF_SHORTS 32768                    // shorts per buf (16 fb x 2 pl x 1024)
#define WS_RB_OFF  (2 * PLANE * 2)          // bytes: after weight planes
#define WS_FLAG_OFF (WS_RB_OFF + (size_t)NGRP * RB_GRP_BYTES)
#define FLAGS_PER_GRP 1024                  // 64 flags x 16-dword pad

typedef __attribute__((ext_vector_type(8))) short bf16x8;
typedef __attribute__((ext_vector_type(4))) float f32x4;
typedef __attribute__((ext_vector_type(4))) unsigned u32x4;

__device__ __forceinline__ float fast_tanh(float x) {
    float e = __expf(2.0f * x);
    return 1.0f - 2.0f * __builtin_amdgcn_rcpf(e + 1.0f);
}

__device__ __forceinline__ void split_hl(float v, unsigned short& h, unsigned short& l) {
    __hip_bfloat16 hb = __float2bfloat16(v);
    h = __builtin_bit_cast(unsigned short, hb);
    l = __builtin_bit_cast(unsigned short, __float2bfloat16(v - __bfloat162float(hb)));
}

// ---- scoped memory helpers -------------------------------------------------
// MALL (device) scope: sc0 sc1 — registration + cross-XCD fallback path.
// L2 (XCD) scope: sc0 only — valid when a group's 16 blocks share one XCD's L2
// (verified at runtime via HW_REG_XCC_ID). Atomics without sc bits execute at L2.
__device__ __forceinline__ unsigned mall_load1(const unsigned* p) {
    unsigned r;
    asm volatile("global_load_dword %0, %1, off sc0 sc1" : "=v"(r) : "v"(p));
    return r;
}
__device__ __forceinline__ unsigned l2_load1(const unsigned* p) {
    unsigned r;
    asm volatile("global_load_dword %0, %1, off sc0" : "=v"(r) : "v"(p));
    return r;
}
__device__ __forceinline__ void mall_store1(unsigned* p, unsigned v) {
    asm volatile("global_store_dword %0, %1, off sc0 sc1" :: "v"(p), "v"(v) : "memory");
}
__device__ __forceinline__ u32x4 mall_load4s(const unsigned short* p) {
    u32x4 r;
    asm volatile("global_load_dwordx4 %0, %1, off sc0 sc1" : "=v"(r) : "v"(p));
    return r;
}
__device__ __forceinline__ u32x4 l2_load4s(const unsigned short* p) {
    u32x4 r;
    asm volatile("global_load_dwordx4 %0, %1, off sc0" : "=v"(r) : "v"(p));
    return r;
}
__device__ __forceinline__ void mall_store4(unsigned short* p, u32x4 v) {
    asm volatile("global_store_dwordx4 %0, %1, off sc0 sc1" :: "v"(p), "v"(v) : "memory");
}
__device__ __forceinline__ void l2_store4(unsigned short* p, u32x4 v) {
    asm volatile("global_store_dwordx4 %0, %1, off sc0" :: "v"(p), "v"(v) : "memory");
}
__device__ __forceinline__ void atom_add_l2(unsigned* p, unsigned v) {
    asm volatile("global_atomic_add %0, %1, off" :: "v"(p), "v"(v) : "memory");
}
__device__ __forceinline__ void atom_addf_l2(float* p, float v) {
    asm volatile("global_atomic_add_f32 %0, %1, off" :: "v"(p), "v"(v) : "memory");
}
__device__ __forceinline__ void wait_vm0() {
    asm volatile("s_waitcnt vmcnt(0)" ::: "memory");
}
__device__ __forceinline__ void wait_lgkm0() {
    asm volatile("s_waitcnt lgkmcnt(0)" ::: "memory");
}

// spin until ALL 16 producer flags of this mt-plane reach `want`
__device__ __forceinline__ void spin_all(const unsigned* fladdr, unsigned want, bool l2m) {
    unsigned guard = 0;
    for (;;) {
        unsigned fv = l2m ? l2_load1(fladdr) : mall_load1(fladdr);
        wait_vm0();
        if (__ballot(fv < want) == 0ull) break;
        __builtin_amdgcn_s_sleep(1);
        if (++guard > (1u << 20)) break;   // bounded: no hang if non-resident
    }
}

__global__ void conv_w(const float* __restrict__ B1, const float* __restrict__ B2,
                       __hip_bfloat16* __restrict__ wh, __hip_bfloat16* __restrict__ wl) {
    int idx = blockIdx.x * 256 + threadIdx.x;
    float v = (idx < RESN * RESN) ? B1[idx] : B2[idx - RESN * RESN];
    __hip_bfloat16 h = __float2bfloat16(v);
    wh[idx] = h;
    wl[idx] = __float2bfloat16(v - __bfloat162float(h));
}

// Weight-stationary persistent kernel. 256 blocks (1/CU), 16 groups x 16 blocks.
// 4 waves = 4 independent mt-planes, barrier-free main loop with per-(fb,mt)
// monotone flags. Exchange buffer is FB-MAJOR: each block owns a contiguous
// 4 KB region per buf, published as fully-covered 512 B runs (1 dwordx4/lane
// via a tiny LDS transpose) -> no partial-line RMW, L2-residency possible.
// Output column is computed DISTRIBUTED: each wave reduces Wr[f]*r over its 16
// feature lanes (shfl_xor) and atomically accumulates fp32 partials into out —
// removes the rotating-leader skew, the Wr staging, and the final-column sync.
__global__ __launch_bounds__(NTHR, 1) void sde_ws(
    const float* __restrict__ Vn,  const float* __restrict__ inc,
    const float* __restrict__ W1,  const float* __restrict__ b1,
    const float* __restrict__ W2,  const float* __restrict__ b2,
    const float* __restrict__ rho1p, const float* __restrict__ rho2p,
    const float* __restrict__ rho3p, const float* __restrict__ rho4p,
    const float* __restrict__ rho5p,
    const float* __restrict__ lam1, const float* __restrict__ lam2,
    const float* __restrict__ Wr,  const float* __restrict__ brp,
    const __hip_bfloat16* __restrict__ wbf,   // hi plane; lo at +PLANE
    unsigned short* __restrict__ rbs,         // r exchange: fb-major hi/lo bf16
    unsigned int* __restrict__ flags,         // [g][(fb*4+mt)*16] monotone, + reg area
    float* __restrict__ out)
{
    __shared__ __align__(16) short wlds[2][NMAT][8][64][8];    // 147,456 B
    __shared__ __align__(16) unsigned short stage[4][512];     // 4,096 B publish stage
    __shared__ int l2mode_sh;

    const int tid  = threadIdx.x;
    const int mt   = tid >> 6;       // wave = mt-plane (batch 16mt..16mt+15)
    const int lane = tid & 63;
    const int n16  = lane & 15;
    const int quad = lane >> 4;
    const int bx   = blockIdx.x;
    const int g    = ((bx & 7) << 1) | (bx >> 7);   // XCD grouping (verified below)
    const int fb   = (bx >> 3) & 15;
    const int f0   = fb * FPB;
    const int b0g  = g * BG;
    unsigned short* gbs = rbs + (size_t)g * GRP_SHORTS;
    unsigned int* flagp  = flags + g * FLAGS_PER_GRP;
    unsigned int* myflag = flagp + (fb * 4 + mt) * 16;
    const unsigned* fladdr = (const unsigned*)(flagp + ((lane & 15) * 4 + mt) * 16);
    unsigned* regtbl = flags + NGRP * FLAGS_PER_GRP;   // [256] physical XCD per block
    unsigned* regcnt = regtbl + 256;

    // ---- XCD registration: post early, decide before phase-B publish ----
    if (tid == 0) {
        unsigned xcd;
        asm volatile("s_getreg_b32 %0, hwreg(HW_REG_XCC_ID)" : "=s"(xcd));
        mall_store1(&regtbl[bx], xcd);
        wait_vm0();
        __hip_atomic_fetch_add(regcnt, 1u, __ATOMIC_RELAXED, __HIP_MEMORY_SCOPE_AGENT);
    }

    const float rho1 = rho1p[0], rho2 = rho2p[0], rho3 = rho3p[0],
                rho4 = rho4p[0], rho5 = rho5p[0];
    const float brv = brp[0];
    const float bradd = (fb == 0) ? brv : 0.0f;   // br added exactly once per out elem

    // ---- phase A: h = tanh(Vn@W1^T+b1) into LDS overlay ----
    float* hf  = (float*)&wlds[0][0][0][0][0];   // [64][66]
    float* vsh = hf + 64 * 66;                   // [64][16]
    for (int p = tid; p < BG * HD; p += NTHR) {
        int b = p >> 6, hh = p & 63;
        float s = b1[hh];
        #pragma unroll
        for (int d = 0; d < DIN; ++d) s += Vn[(b0g + b) * DIN + d] * W1[hh * DIN + d];
        hf[b * 66 + hh] = fast_tanh(s);
    }
    __syncthreads();

    // ---- XCD-residency decision: L2 scope iff all 16 group members share an XCD.
    if (tid == 0) {
        unsigned cnt, guard = 0;
        do {
            cnt = mall_load1(regcnt);
            wait_vm0();
            if (cnt >= 256) break;
            __builtin_amdgcn_s_sleep(1);
        } while (++guard < (1u << 22));
        unsigned e[16];
        #pragma unroll
        for (int q = 0; q < 16; ++q)
            e[q] = mall_load1(&regtbl[((g & 1) << 7) | (q << 3) | (g >> 1)]);
        wait_vm0();
        int ok = (cnt >= 256) ? 1 : 0;
        #pragma unroll
        for (int q = 1; q < 16; ++q) ok &= (e[q] == e[0]) ? 1 : 0;
        l2mode_sh = ok;
    }
    __syncthreads();
    const bool l2m = (l2mode_sh != 0);

    // ---- phase B: V slice; publish r0 into buf 0 (fb-major, full-line) ----
    {
        int bl = lane >> 2;                       // local batch 0..15
        int b  = 16 * mt + bl;
        #pragma unroll
        for (int i = 0; i < 4; ++i) {
            int f = (lane & 3) * 4 + i;
            float s = b2[f0 + f];
            #pragma unroll 8
            for (int hh = 0; hh < HD; ++hh) s += hf[b * 66 + hh] * W2[(f0 + f) * HD + hh];
            vsh[b * 16 + f] = s;
            unsigned short h_, l_;
            split_hl(s, h_, l_);
            stage[mt][0 * 256 + bl * 16 + f] = h_;
            stage[mt][1 * 256 + bl * 16 + f] = l_;
        }
        wait_lgkm0();
        u32x4 v = *(const u32x4*)&stage[mt][lane * 8];
        unsigned short* dst = gbs + 0 * BUF_SHORTS + fb * 2048 +
                              (lane >> 5) * 1024 + 16 * mt * 16 + (lane & 31) * 8;
        if (l2m) l2_store4(dst, v); else mall_store4(dst, v);
    }
    wait_vm0();
    if (lane == 0) {
        if (l2m) atom_add_l2(myflag, 1u);
        else __hip_atomic_fetch_add(myflag, 1u, __ATOMIC_RELAXED, __HIP_MEMORY_SCOPE_AGENT);
    }

    // ---- phase C: per-lane state (wave-local reads of vsh) ----
    float rmast[4];   // fp32 master r: batch = 16mt+4quad+rg, feature = f0+n16
    #pragma unroll
    for (int rg = 0; rg < 4; ++rg) rmast[rg] = vsh[(16 * mt + 4 * quad + rg) * 16 + n16];
    const float l1c = lam1[f0 + n16];
    const float wrv = Wr[f0 + n16];
    float l2c[BDN];
    #pragma unroll
    for (int k = 0; k < BDN; ++k) l2c[k] = lam2[k * RESN + f0 + n16];
    __syncthreads();   // all vsh/hf reads done before weight overwrite

    // ---- phase D: weight slice -> fragment-major LDS ----
    for (int e = tid; e < 2 * NMAT * 8 * 64; e += NTHR) {
        int l  = e & 63;
        int kk = (e >> 6) & 7;
        int m  = e >> 9;
        int pl = (m >= NMAT) ? 1 : 0;
        int nt = m - pl * NMAT;
        const uint4* src = (const uint4*)(wbf + (size_t)pl * PLANE +
            (size_t)(nt * RESN + f0 + (l & 15)) * RESN + kk * 32 + (l >> 4) * 8);
        *(uint4*)&wlds[pl][nt][kk][l][0] = *src;
    }
    __syncthreads();

    // consumer A-load base: lane reads batch 16mt+n16, 8 feats per kk-quad chunk
    const unsigned short* pcb = gbs + (quad >> 1) * 2048 + (16 * mt + n16) * 16 + (quad & 1) * 8;

    // ---- main loop: barrier-free ----
    for (int t = 0; t < L_T; ++t) {
        // out column t from CURRENT rmast (= r_t): fp32 partial, shfl-reduce over
        // the 16 feature lanes, one float atomic per (batch,t) per block.
        {
            float po[4];
            #pragma unroll
            for (int rg = 0; rg < 4; ++rg) {
                float p = wrv * rmast[rg];
                p += __shfl_xor(p, 1);
                p += __shfl_xor(p, 2);
                p += __shfl_xor(p, 4);
                p += __shfl_xor(p, 8);
                po[rg] = p;
            }
            if (n16 == 0) {
                #pragma unroll
                for (int rg = 0; rg < 4; ++rg) {
                    float* op = out + (size_t)(b0g + 16 * mt + 4 * quad + rg) * L_T + t;
                    float v = po[rg] + bradd;
                    if (l2m) atom_addf_l2(op, v);
                    else __hip_atomic_fetch_add(op, v, __ATOMIC_RELAXED, __HIP_MEMORY_SCOPE_AGENT);
                }
            }
        }
        if (t == L_T - 1) break;   // column 127 emitted; no step-128 compute

        // dw loads (independent of exchange) issued first
        float dwv[4][8];
        #pragma unroll
        for (int rg = 0; rg < 4; ++rg) {
            const size_t bglob = (size_t)(b0g + 16 * mt + 4 * quad + rg) * (L_T * BDN);
            const float4 d0 = *(const float4*)(inc + bglob + (size_t)(t + 1) * BDN);
            const float4 d1 = *(const float4*)(inc + bglob + (size_t)(t + 1) * BDN + 4);
            dwv[rg][0] = d0.x; dwv[rg][1] = d0.y; dwv[rg][2] = d0.z; dwv[rg][3] = d0.w;
            dwv[rg][4] = d1.x; dwv[rg][5] = d1.y; dwv[rg][6] = d1.z; dwv[rg][7] = d1.w;
            if (t == 0) {
                const float4 e0 = *(const float4*)(inc + bglob);
                const float4 e1 = *(const float4*)(inc + bglob + 4);
                dwv[rg][0] += e0.x; dwv[rg][1] += e0.y; dwv[rg][2] += e0.z; dwv[rg][3] += e0.w;
                dwv[rg][4] += e1.x; dwv[rg][5] += e1.y; dwv[rg][6] += e1.z; dwv[rg][7] += e1.w;
            }
        }
        spin_all(fladdr, (unsigned)(t + 1), l2m);
        const int cur = t & 1, nxt = cur ^ 1;

        // A-frags: direct bf16x8 loads from fb-major regions, single waitcnt
        bf16x8 afh[8], afl[8];
        {
            const unsigned short* pc = pcb + cur * BUF_SHORTS;
            if (l2m) {
                #pragma unroll
                for (int kk = 0; kk < 8; ++kk) {
                    afh[kk] = __builtin_bit_cast(bf16x8, l2_load4s(pc + kk * 4096));
                    afl[kk] = __builtin_bit_cast(bf16x8, l2_load4s(pc + kk * 4096 + 1024));
                }
            } else {
                #pragma unroll
                for (int kk = 0; kk < 8; ++kk) {
                    afh[kk] = __builtin_bit_cast(bf16x8, mall_load4s(pc + kk * 4096));
                    afl[kk] = __builtin_bit_cast(bf16x8, mall_load4s(pc + kk * 4096 + 1024));
                }
            }
        }
        wait_vm0();

        // 9 matvecs, 3-term double-bf16: ah*bh + al*bh + ah*bl
        f32x4 acc[NMAT] = {};
        #pragma unroll
        for (int kk = 0; kk < 8; ++kk) {
            bf16x8 bh[NMAT], bl[NMAT];
            #pragma unroll
            for (int nt = 0; nt < NMAT; ++nt) {
                bh[nt] = *(const bf16x8*)&wlds[0][nt][kk][lane][0];
                bl[nt] = *(const bf16x8*)&wlds[1][nt][kk][lane][0];
            }
            #pragma unroll
            for (int nt = 0; nt < NMAT; ++nt)
                acc[nt] = __builtin_amdgcn_mfma_f32_16x16x32_bf16(afh[kk], bh[nt], acc[nt], 0, 0, 0);
            #pragma unroll
            for (int nt = 0; nt < NMAT; ++nt)
                acc[nt] = __builtin_amdgcn_mfma_f32_16x16x32_bf16(afl[kk], bh[nt], acc[nt], 0, 0, 0);
            #pragma unroll
            for (int nt = 0; nt < NMAT; ++nt)
                acc[nt] = __builtin_amdgcn_mfma_f32_16x16x32_bf16(afh[kk], bl[nt], acc[nt], 0, 0, 0);
        }

        // combine; stage hi/lo slice in LDS; one dwordx4 store/lane; flag post
        #pragma unroll
        for (int rg = 0; rg < 4; ++rg) {
            float drift = fast_tanh(rho1 * acc[0][rg] + rho2 * l1c);
            float s = 0.0f;
            #pragma unroll
            for (int k = 0; k < BDN; ++k)
                s += fast_tanh(rho3 * acc[1 + k][rg] + rho4 * l2c[k]) * dwv[rg][k];
            float rn = rmast[rg] + drift + rho5 * s;
            rmast[rg] = rn;
            unsigned short h_, l_;
            split_hl(rn, h_, l_);
            stage[mt][0 * 256 + (4 * quad + rg) * 16 + n16] = h_;
            stage[mt][1 * 256 + (4 * quad + rg) * 16 + n16] = l_;
        }
        wait_lgkm0();
        {
            u32x4 v = *(const u32x4*)&stage[mt][lane * 8];
            unsigned short* dst = gbs + nxt * BUF_SHORTS + fb * 2048 +
                                  (lane >> 5) * 1024 + 16 * mt * 16 + (lane & 31) * 8;
            if (l2m) l2_store4(dst, v); else mall_store4(dst, v);
        }
        wait_vm0();
        if (lane == 0) {
            if (l2m) atom_add_l2(myflag, 1u);
            else __hip_atomic_fetch_add(myflag, 1u, __ATOMIC_RELAXED, __HIP_MEMORY_SCOPE_AGENT);
        }
    }
}

extern "C" void kernel_launch(void* const* d_in, const int* in_sizes, int n_in,
                              void* d_out, int out_size, void* d_ws, size_t ws_size,
                              hipStream_t stream) {
    const float* Vn   = (const float*)d_in[0];
    const float* inc  = (const float*)d_in[1];
    const float* W1   = (const float*)d_in[2];
    const float* b1   = (const float*)d_in[3];
    const float* W2   = (const float*)d_in[4];
    const float* b2   = (const float*)d_in[5];
    const float* r1   = (const float*)d_in[6];
    const float* r2   = (const float*)d_in[7];
    const float* r3   = (const float*)d_in[8];
    const float* r4   = (const float*)d_in[9];
    const float* r5   = (const float*)d_in[10];
    const float* B1   = (const float*)d_in[11];
    const float* B2   = (const float*)d_in[12];
    const float* lam1 = (const float*)d_in[13];
    const float* lam2 = (const float*)d_in[14];
    const float* Wr   = (const float*)d_in[15];
    const float* br   = (const float*)d_in[16];

    __hip_bfloat16* wh    = (__hip_bfloat16*)d_ws;
    unsigned short* rbs   = (unsigned short*)((char*)d_ws + WS_RB_OFF);
    unsigned int*   flags = (unsigned int*)((char*)d_ws + WS_FLAG_OFF);
    float* out = (float*)d_out;

    // out accumulated via atomics -> must start zeroed
    hipMemsetAsync(d_out, 0, out_size, stream);
    // flags + XCD registration table/counter (256 dwords + 1, padded)
    hipMemsetAsync(flags, 0, NGRP * FLAGS_PER_GRP * sizeof(unsigned int) + 2048, stream);
    conv_w<<<dim3(NROWS * RESN / 256), dim3(256), 0, stream>>>(B1, B2, wh, wh + PLANE);
    sde_ws<<<dim3(256), dim3(NTHR), 0, stream>>>(
        Vn, inc, W1, b1, W2, b2, r1, r2, r3, r4, r5, lam1, lam2, Wr, br,
        wh, rbs, flags, out);
}